// Round 15
// baseline (84.455 us; speedup 1.0000x reference)
//
#include <hip/hip_runtime.h>
#include <hip/hip_bf16.h>

#define NHID 512
#define PROJ 64
#define NC 4096
#define NEV 8192
#define NG 64
#define NCMAX 128
#define NE_CAP 256
#define DSLICES 4
#define DW 128
#define MAGIC 0x7E57C0DE

typedef __attribute__((ext_vector_type(8))) short s16x8;
typedef __attribute__((ext_vector_type(8))) unsigned short u16x8;
typedef __attribute__((ext_vector_type(4))) float f32x4;

// ---- k_attn LDS layout (bytes) ----
#define P_S_STRIDE 264            // bf16 elems per row (256 + 8 pad), 528B
#define P_S_BYTES  (NCMAX * P_S_STRIDE * 2)        // 67584
#define REGB_OFF   P_S_BYTES
#define WE_S_STRIDE 72            // bf16 elems (64 + 8 pad), 144B
#define WC_S_OFF   (REGB_OFF + NE_CAP * WE_S_STRIDE * 2)
#define CN_S_STRIDE 132           // f32 elems per row
#define SMEM_BYTES (REGB_OFF + P_S_BYTES)

static __device__ __forceinline__ unsigned short f2b(float f) {
  union { __hip_bfloat16 h; unsigned short u; } v;
  v.h = __float2bfloat16(f);
  return v.u;
}
static __device__ __forceinline__ float b2f(unsigned short u) {
  union { unsigned short u; __hip_bfloat16 h; } v;
  v.u = u;
  return __bfloat162float(v.h);
}

// ---------------- compact_pairs: stable compaction -> (orig_pos, node_id) ----------------
template <int NPT>
__device__ __forceinline__ void compact_pairs(
    const int* __restrict__ batch, const int* __restrict__ idx, int g,
    int* __restrict__ off_out, int* __restrict__ cnt_out, int2* __restrict__ pairs) {
  __shared__ int wtot[4], wless[4];
  int t = threadIdx.x, lane = t & 63, w = t >> 6;
  int vals[NPT], nid[NPT];
  int base_i = t * NPT;
  int eq = 0, less = 0;
#pragma unroll
  for (int j = 0; j < NPT; j++) {
    int node = idx[base_i + j];
    int v = batch[node];
    vals[j] = v;
    nid[j] = node;
    eq += (v == g) ? 1 : 0;
    less += (v < g) ? 1 : 0;
  }
  int s = eq;
#pragma unroll
  for (int off = 1; off < 64; off <<= 1) {
    int o = __shfl_up(s, off);
    if (lane >= off) s += o;
  }
  int ls = less;
#pragma unroll
  for (int off = 32; off; off >>= 1) ls += __shfl_xor(ls, off);
  if (lane == 63) wtot[w] = s;
  if (lane == 0) wless[w] = ls;
  __syncthreads();
  int wbase = 0;
#pragma unroll
  for (int k = 0; k < 4; k++)
    if (k < w) wbase += wtot[k];
  int base = wless[0] + wless[1] + wless[2] + wless[3];
  int pos = base + wbase + (s - eq);
#pragma unroll
  for (int j = 0; j < NPT; j++) {
    if (vals[j] == g) pairs[pos++] = make_int2(base_i + j, nid[j]);
  }
  if (t == 255) {
    cnt_out[g] = wbase + s;
    off_out[g] = base;
  }
}

// ---------------- k_fused: transposes + compaction + projection GEMM in ONE launch ----------------
// All 1168 blocks (256 thr, <=17KB LDS) are co-resident (>=8 blocks/CU) -> spin-wait is safe.
// GEMM blocks wait on per-graph MAGIC flags (poison-proof, replay-idempotent).
__global__ __launch_bounds__(256) void k_fused(
    const float* __restrict__ x, const float* __restrict__ Wc,
    const float* __restrict__ We, const float* __restrict__ Wa,
    const int* __restrict__ batch, const int* __restrict__ cidx,
    const int* __restrict__ eidx, unsigned short* __restrict__ WcT,
    unsigned short* __restrict__ WeT, unsigned short* __restrict__ WaT,
    int* __restrict__ c_off, int* __restrict__ c_cnt, int2* __restrict__ c_pair,
    int* __restrict__ e_off, int* __restrict__ e_cnt, int2* __restrict__ e_pair,
    const float* __restrict__ bc, const float* __restrict__ be,
    unsigned short* __restrict__ wcp_c, unsigned short* __restrict__ wep_c,
    unsigned short* __restrict__ xc_c, unsigned short* __restrict__ xe_c,
    int* __restrict__ c_flag, int* __restrict__ e_flag) {
  __shared__ __align__(16) char sm[64 * 65 * 4];
  int b = blockIdx.x;
  int t = threadIdx.x;

  if (b < 16) {
    // ---- Wc/We f32[512][64] -> bf16 [64][512] transpose ----
    float(*ts)[65] = (float(*)[65])sm;
    const float* src = (b < 8) ? Wc : We;
    unsigned short* dst = (b < 8) ? WcT : WeT;
    int k0 = (b & 7) * 64;
    int c = t & 63, r0 = t >> 6;
#pragma unroll
    for (int p = 0; p < 16; p++) {
      int r = r0 * 16 + p;
      ts[r][c] = src[(size_t)(k0 + r) * 64 + c];
    }
    __syncthreads();
    int n = t >> 2, q = t & 3;
    unsigned short tmp[16];
#pragma unroll
    for (int j = 0; j < 16; j++) tmp[j] = f2b(ts[q * 16 + j][n]);
    u16x8* dp = (u16x8*)(dst + (size_t)n * NHID + k0 + q * 16);
    dp[0] = *(u16x8*)tmp;
    dp[1] = *(u16x8*)(tmp + 8);
    return;
  }
  if (b < 80) {
    // ---- claim compaction for graph g ----
    int g = b - 16;
    compact_pairs<NC / 256>(batch, cidx, g, c_off, c_cnt, c_pair);
    __syncthreads();
    if (t == 0) {
      __threadfence();
      __hip_atomic_store(&c_flag[g], MAGIC, __ATOMIC_RELEASE, __HIP_MEMORY_SCOPE_AGENT);
    }
    return;
  }
  if (b < 144) {
    // ---- evidence compaction for graph g ----
    int g = b - 80;
    compact_pairs<NEV / 256>(batch, eidx, g, e_off, e_cnt, e_pair);
    __syncthreads();
    if (t == 0) {
      __threadfence();
      __hip_atomic_store(&e_flag[g], MAGIC, __ATOMIC_RELEASE, __HIP_MEMORY_SCOPE_AGENT);
    }
    return;
  }
  if (b < 400) {
    // ---- Wa f32[2048][512] -> bf16 [512][2048] transpose, 64x64 tiles ----
    int tb = b - 144;
    float(*ts)[65] = (float(*)[65])sm;
    int k0 = (tb >> 3) * 64, n0 = (tb & 7) * 64;
    int c = t & 63, r0 = t >> 6;
#pragma unroll
    for (int p = 0; p < 16; p++) {
      int r = r0 * 16 + p;
      ts[r][c] = Wa[(size_t)(k0 + r) * NHID + n0 + c];
    }
    __syncthreads();
    int n = t >> 2, q = t & 3;
    unsigned short tmp[16];
#pragma unroll
    for (int j = 0; j < 16; j++) tmp[j] = f2b(ts[q * 16 + j][n]);
    u16x8* dp = (u16x8*)(WaT + (size_t)(n0 + n) * (4 * NHID) + k0 + q * 16);
    dp[0] = *(u16x8*)tmp;
    dp[1] = *(u16x8*)(tmp + 8);
    return;
  }

  // ---- projection GEMM (768 blocks: 256 claim, 512 evidence) ----
  int gb = b - 400;
  const int2* pair; const unsigned short* WT; const float* bias;
  unsigned short* out; unsigned short* xout; int base; const int* flg;
  if (gb < NC / 16) {
    pair = c_pair; WT = WcT; bias = bc; out = wcp_c; xout = xc_c;
    base = gb * 16; flg = c_flag;
  } else {
    pair = e_pair; WT = WeT; bias = be; out = wep_c; xout = xe_c;
    base = (gb - NC / 16) * 16; flg = e_flag;
  }
  int lane = t & 63, kh = t >> 6;
  // spin until this side's compaction is complete (all 64 graph flags)
  {
    while (true) {
      int v = (lane < NG)
                  ? __hip_atomic_load(&flg[lane], __ATOMIC_ACQUIRE, __HIP_MEMORY_SCOPE_AGENT)
                  : MAGIC;
      if (__all(v == MAGIC)) break;
      __builtin_amdgcn_s_sleep(1);
    }
  }
  float(*red)[16][64] = (float(*)[16][64])sm;   // [4][16][64] = 16KB
  int ln = lane & 15, kb = lane >> 4;
  const float* xr = x + (size_t)pair[base + ln].y * NHID + kh * 128;
  unsigned short* xw = xout + (size_t)(base + ln) * NHID + kh * 128;
  const unsigned short* wb = WT + kh * 128;
  f32x4 acc[4];
#pragma unroll
  for (int nt = 0; nt < 4; nt++) acc[nt] = (f32x4){0.f, 0.f, 0.f, 0.f};
#pragma unroll
  for (int kt = 0; kt < 4; kt++) {
    int k0 = kt * 32 + kb * 8;
    float4 p0 = *(const float4*)(xr + k0);
    float4 p1 = *(const float4*)(xr + k0 + 4);
    s16x8 a;
    a[0] = (short)f2b(p0.x); a[1] = (short)f2b(p0.y);
    a[2] = (short)f2b(p0.z); a[3] = (short)f2b(p0.w);
    a[4] = (short)f2b(p1.x); a[5] = (short)f2b(p1.y);
    a[6] = (short)f2b(p1.z); a[7] = (short)f2b(p1.w);
    *(u16x8*)(xw + k0) = (u16x8)a;   // export bf16 row (compacted order)
#pragma unroll
    for (int nt = 0; nt < 4; nt++) {
      s16x8 bf = *(const s16x8*)(wb + (size_t)(nt * 16 + ln) * NHID + k0);
      acc[nt] = __builtin_amdgcn_mfma_f32_16x16x32_bf16(a, bf, acc[nt], 0, 0, 0);
    }
  }
#pragma unroll
  for (int nt = 0; nt < 4; nt++)
#pragma unroll
    for (int r = 0; r < 4; r++)
      red[kh][kb * 4 + r][nt * 16 + ln] = acc[nt][r];
  __syncthreads();
  for (int i = t; i < 512; i += 256) {
    int row = i >> 5, cp = i & 31;
    int c0 = cp * 2;
    float v0 = red[0][row][c0] + red[1][row][c0] + red[2][row][c0] + red[3][row][c0] + bias[c0];
    float v1 = red[0][row][c0 + 1] + red[1][row][c0 + 1] + red[2][row][c0 + 1] + red[3][row][c0 + 1] + bias[c0 + 1];
    unsigned int pk = (unsigned)f2b(v0) | ((unsigned)f2b(v1) << 16);
    *(unsigned int*)(out + (size_t)(base + row) * PROJ + c0) = pk;
  }
}

// ---------------- k_attn: MFMA attention, dynamic bounds + wave-uniform skips ----------------
__global__ __launch_bounds__(512, 2) void k_attn(
    const unsigned short* __restrict__ xc_c, const unsigned short* __restrict__ xe_c,
    const unsigned short* __restrict__ wcp_c, const unsigned short* __restrict__ wep_c,
    const int* __restrict__ c_off, const int* __restrict__ c_cnt,
    const int* __restrict__ e_off, const int* __restrict__ e_cnt,
    unsigned short* __restrict__ mcb) {
  __shared__ __align__(16) char smem[SMEM_BYTES];
  unsigned short* P_s  = (unsigned short*)(smem);
  unsigned short* we_s = (unsigned short*)(smem + REGB_OFF);
  unsigned short* wc_s = (unsigned short*)(smem + WC_S_OFF);
  unsigned short* evT  = (unsigned short*)(smem + REGB_OFF);
  unsigned int*   evT32 = (unsigned int*)(smem + REGB_OFF);
  float*          cn_s = (float*)(smem + REGB_OFF);
  float*          pp   = (float*)(smem);          // reuses dead P_s region post-PV

  int g = blockIdx.x >> 2;
  int ds = blockIdx.x & 3;
  int dsbase = ds * DW;
  int t = threadIdx.x, lane = t & 63, w = t >> 6;
  int ln = lane & 15, kb = lane >> 4;

  int ne = min(e_cnt[g], NE_CAP);
  int eoff = e_off[g];
  int ccnt_full = c_cnt[g];
  int nloc = min(ccnt_full, NCMAX);
  int coff = c_off[g];
  if (nloc <= 0) {
    int q = t >> 7, d = t & 127;
    mcb[(size_t)g * 4 * NHID + q * NHID + dsbase + d] = 0;
    return;
  }
  int KT = (ne + 31) >> 5;
  int NT = KT * 2;
  int ne32 = KT * 32;                 // ceil32(ne)
  int npair = ne32 >> 1;
  int nc16 = (nloc + 15) & ~15;       // ceil16(nloc)

  // ---- phase 0: stage we_s + wc_s (contiguous, dynamic bounds) ----
  {
    int q = t & 7, er = t >> 3;
    for (int base_ = 0; base_ < ne32; base_ += 64) {
      int e = base_ + er;
      if (e < ne32) {
        u16x8 v = (u16x8){0, 0, 0, 0, 0, 0, 0, 0};
        if (e < ne) v = *(const u16x8*)(wep_c + (size_t)(eoff + e) * PROJ + q * 8);
        *(u16x8*)(we_s + e * WE_S_STRIDE + q * 8) = v;
      }
    }
    for (int base_ = 0; base_ < nc16; base_ += 64) {
      int c = base_ + er;
      if (c < nc16) {
        u16x8 v = (u16x8){0, 0, 0, 0, 0, 0, 0, 0};
        if (c < nloc) v = *(const u16x8*)(wcp_c + (size_t)(coff + c) * PROJ + q * 8);
        *(u16x8*)(wc_s + c * WE_S_STRIDE + q * 8) = v;
      }
    }
  }
  __syncthreads();

  // ---- score phase: only waves whose 16-claim tile is live ----
  if ((w << 4) < nloc) {
    f32x4 sa[16];
#pragma unroll
    for (int i = 0; i < 16; i++) sa[i] = (f32x4){0.f, 0.f, 0.f, 0.f};
    const unsigned short* arow = wc_s + ((w << 4) + ln) * WE_S_STRIDE;
#pragma unroll
    for (int ks = 0; ks < 2; ks++) {
      s16x8 af = *(const s16x8*)(arow + ks * 32 + kb * 8);
#pragma unroll
      for (int nt = 0; nt < 16; nt++) {
        if (nt < NT) {
          s16x8 bf = *(const s16x8*)(we_s + (nt * 16 + ln) * WE_S_STRIDE + ks * 32 + kb * 8);
          sa[nt] = __builtin_amdgcn_mfma_f32_16x16x32_bf16(af, bf, sa[nt], 0, 0, 0);
        }
      }
    }
#pragma unroll
    for (int r = 0; r < 4; r++) {
      int claim = (w << 4) + (kb << 2) + r;
      float mx = -1e30f;
#pragma unroll
      for (int nt = 0; nt < 16; nt++) {
        if (nt < NT) {
          float v = sa[nt][r];
          v = (nt * 16 + ln < ne) ? v : -1e30f;
          sa[nt][r] = v;
          mx = fmaxf(mx, v);
        }
      }
      mx = fmaxf(mx, __shfl_xor(mx, 1));
      mx = fmaxf(mx, __shfl_xor(mx, 2));
      mx = fmaxf(mx, __shfl_xor(mx, 4));
      mx = fmaxf(mx, __shfl_xor(mx, 8));
      float sum = 0.f;
#pragma unroll
      for (int nt = 0; nt < 16; nt++) {
        if (nt < NT) {
          float p = __expf(sa[nt][r] - mx);
          sa[nt][r] = p;
          sum += p;
        }
      }
      sum += __shfl_xor(sum, 1);
      sum += __shfl_xor(sum, 2);
      sum += __shfl_xor(sum, 4);
      sum += __shfl_xor(sum, 8);
      float inv = 1.f / sum;
#pragma unroll
      for (int nt = 0; nt < 16; nt++) {
        if (nt < NT)
          P_s[claim * P_S_STRIDE + nt * 16 + ln] = f2b(sa[nt][r] * inv);
      }
    }
  }
  __syncthreads();   // we_s dead; P_s ready (live rows only)

  // ---- evT staging: contiguous bf16 slab, dynamic pair count ----
#pragma unroll
  for (int it = 0; it < 4; it++) {
    int idx2 = it * 512 + t;              // [ep_hi:4][j8:4][ep_lo:3]
    int ep = ((idx2 >> 7) << 3) | (idx2 & 7);
    int j8 = (idx2 >> 3) & 15;
    if (ep < npair) {
      int d0 = j8 * 8;
      int e0 = ep * 2;
      u16x8 va = (u16x8){0, 0, 0, 0, 0, 0, 0, 0};
      u16x8 vb = (u16x8){0, 0, 0, 0, 0, 0, 0, 0};
      if (e0 < ne)     va = *(const u16x8*)(xe_c + (size_t)(eoff + e0) * NHID + dsbase + d0);
      if (e0 + 1 < ne) vb = *(const u16x8*)(xe_c + (size_t)(eoff + e0 + 1) * NHID + dsbase + d0);
#pragma unroll
      for (int j = 0; j < 8; j++)
        evT32[(d0 + j) * (P_S_STRIDE / 2) + ep] =
            (unsigned)(unsigned short)va[j] | ((unsigned)(unsigned short)vb[j] << 16);
    }
  }
  __syncthreads();

  // ---- T14: issue claim-row loads (bf16, contiguous) for pooled phase ----
  int dq4 = (t & 31) * 4;
  int mg = t >> 5;     // 0..15
  ushort4 cl_u[8];
#pragma unroll
  for (int mi = 0; mi < 8; mi++) {
    int m = mg + mi * 16;
    cl_u[mi] = make_ushort4(0, 0, 0, 0);
    if (m < nloc)
      cl_u[mi] = *(const ushort4*)(xc_c + (size_t)(coff + m) * NHID + dsbase + dq4);
  }

  // ---- PV phase: only waves whose 32-row tile is live ----
  int mw = w >> 1, nw = w & 1;
  int m0 = mw * 32, n0 = nw * 64;
  f32x4 pc[8];
#pragma unroll
  for (int i = 0; i < 8; i++) pc[i] = (f32x4){0.f, 0.f, 0.f, 0.f};
  bool pv_live = (m0 < nloc);
  if (pv_live) {
    const unsigned short* prow0 = P_s + (m0 + ln) * P_S_STRIDE + kb * 8;
    const unsigned short* prow1 = prow0 + 16 * P_S_STRIDE;
#pragma unroll
    for (int kt = 0; kt < 8; kt++) {
      if (kt < KT) {
        int k0 = kt * 32;
        s16x8 a0 = *(const s16x8*)(prow0 + k0);
        s16x8 a1 = *(const s16x8*)(prow1 + k0);
#pragma unroll
        for (int nt = 0; nt < 4; nt++) {
          s16x8 bf = *(const s16x8*)(evT + (n0 + nt * 16 + ln) * P_S_STRIDE + k0 + kb * 8);
          pc[nt]     = __builtin_amdgcn_mfma_f32_16x16x32_bf16(a0, bf, pc[nt], 0, 0, 0);
          pc[4 + nt] = __builtin_amdgcn_mfma_f32_16x16x32_bf16(a1, bf, pc[4 + nt], 0, 0, 0);
        }
      }
    }
  }
  __syncthreads();   // P_s dead from here; pp may reuse its region

  // ---- dump cn to LDS (live waves only; dead rows never read) ----
  if (pv_live) {
#pragma unroll
    for (int mi = 0; mi < 2; mi++) {
#pragma unroll
      for (int nt = 0; nt < 4; nt++) {
        f32x4 v = pc[mi * 4 + nt];
#pragma unroll
        for (int r = 0; r < 4; r++)
          cn_s[(m0 + mi * 16 + (kb << 2) + r) * CN_S_STRIDE + n0 + nt * 16 + ln] = v[r];
      }
    }
  }
  __syncthreads();

  // ---- pooled sums: staged bf16 claim regs + cn_s, partials into pp ----
  {
    float4 scl = make_float4(0.f, 0.f, 0.f, 0.f);
    float4 scn = make_float4(0.f, 0.f, 0.f, 0.f);
    float4 spr = make_float4(0.f, 0.f, 0.f, 0.f);
#pragma unroll
    for (int mi = 0; mi < 8; mi++) {
      int m = mg + mi * 16;
      if (m < nloc) {
        float clx = b2f(cl_u[mi].x), cly = b2f(cl_u[mi].y);
        float clz = b2f(cl_u[mi].z), clw = b2f(cl_u[mi].w);
        float4 cn = *(const float4*)(cn_s + m * CN_S_STRIDE + dq4);
        scl.x += clx; scl.y += cly; scl.z += clz; scl.w += clw;
        scn.x += cn.x; scn.y += cn.y; scn.z += cn.z; scn.w += cn.w;
        spr.x += clx * cn.x; spr.y += cly * cn.y;
        spr.z += clz * cn.z; spr.w += clw * cn.w;
      }
    }
    *(float4*)(pp + mg * 128 + dq4) = scl;
    *(float4*)(pp + 2048 + mg * 128 + dq4) = scn;
    *(float4*)(pp + 4096 + mg * 128 + dq4) = spr;
  }
  __syncthreads();

  // ---- fused mean-concat epilogue ----
  {
    int q = t >> 7, d = t & 127;
    float inv = 1.f / (float)max(ccnt_full, 1);
    float v = 0.f;
    if (q == 0) {
#pragma unroll
      for (int mg2 = 0; mg2 < 16; mg2++) v += pp[mg2 * 128 + d];
    } else if (q == 1) {
#pragma unroll
      for (int mg2 = 0; mg2 < 16; mg2++) v += pp[2048 + mg2 * 128 + d];
    } else if (q == 2) {
#pragma unroll
      for (int mg2 = 0; mg2 < 16; mg2++) v += pp[mg2 * 128 + d] - pp[2048 + mg2 * 128 + d];
    } else {
#pragma unroll
      for (int mg2 = 0; mg2 < 16; mg2++) v += pp[4096 + mg2 * 128 + d];
    }
    mcb[(size_t)g * 4 * NHID + q * NHID + dsbase + d] = f2b(v * inv);
  }
}

// ---------------- k_out: 32 blocks, 16-col n-tiles, 2-way K-split ----------------
__global__ __launch_bounds__(512) void k_out(
    const unsigned short* __restrict__ mc, const unsigned short* __restrict__ WaT,
    const float* __restrict__ ba, float* __restrict__ out) {
  __shared__ float red[2][64][16];   // 8KB
  int n0 = blockIdx.x * 16;
  int t = threadIdx.x, lane = t & 63, wv = t >> 6;
  int mh = wv & 3, kh = wv >> 2;
  int ln = lane & 15, kb = lane >> 4;
  f32x4 acc = (f32x4){0.f, 0.f, 0.f, 0.f};
  const unsigned short* arow = mc + (size_t)(mh * 16 + ln) * (4 * NHID) + kh * 1024;
  const unsigned short* wcol = WaT + (size_t)(n0 + ln) * (4 * NHID) + kh * 1024;
#pragma unroll 4
  for (int kt = 0; kt < 32; kt++) {
    int k0 = kt * 32 + kb * 8;
    s16x8 af = *(const s16x8*)(arow + k0);
    s16x8 bf = *(const s16x8*)(wcol + k0);
    acc = __builtin_amdgcn_mfma_f32_16x16x32_bf16(af, bf, acc, 0, 0, 0);
  }
#pragma unroll
  for (int r = 0; r < 4; r++)
    red[kh][mh * 16 + kb * 4 + r][ln] = acc[r];
  __syncthreads();
  for (int i = t; i < 1024; i += 512) {
    int row = i >> 4, col = i & 15;
    out[(size_t)row * NHID + n0 + col] = red[0][row][col] + red[1][row][col] + ba[n0 + col];
  }
}

extern "C" void kernel_launch(void* const* d_in, const int* in_sizes, int n_in,
                              void* d_out, int out_size, void* d_ws, size_t ws_size,
                              hipStream_t stream) {
  const float* x = (const float*)d_in[0];
  const int* batch = (const int*)d_in[1];
  const int* cidx = (const int*)d_in[2];
  const int* eidx = (const int*)d_in[3];
  const float* Wc = (const float*)d_in[4];
  const float* bc = (const float*)d_in[5];
  const float* We = (const float*)d_in[6];
  const float* be = (const float*)d_in[7];
  const float* Wa = (const float*)d_in[8];
  const float* ba = (const float*)d_in[9];
  float* out = (float*)d_out;

  char* w = (char*)d_ws;
  int* c_off = (int*)w;    w += NG * 4;
  int* c_cnt = (int*)w;    w += NG * 4;
  int* e_off = (int*)w;    w += NG * 4;
  int* e_cnt = (int*)w;    w += NG * 4;
  int* c_flag = (int*)w;   w += NG * 4;
  int* e_flag = (int*)w;   w += NG * 4;
  int2* c_pair = (int2*)w; w += (size_t)NC * 8;
  int2* e_pair = (int2*)w; w += (size_t)NEV * 8;
  unsigned short* wcp_c = (unsigned short*)w; w += (size_t)NC * PROJ * 2;
  unsigned short* wep_c = (unsigned short*)w; w += (size_t)NEV * PROJ * 2;
  unsigned short* WcT = (unsigned short*)w;   w += (size_t)PROJ * NHID * 2;
  unsigned short* WeT = (unsigned short*)w;   w += (size_t)PROJ * NHID * 2;
  unsigned short* WaT = (unsigned short*)w;   w += (size_t)NHID * 4 * NHID * 2;
  unsigned short* mcb = (unsigned short*)w;   w += (size_t)NG * 4 * NHID * 2;
  unsigned short* xc_c = (unsigned short*)w;  w += (size_t)NC * NHID * 2;
  unsigned short* xe_c = (unsigned short*)w;  w += (size_t)NEV * NHID * 2;

  k_fused<<<1168, 256, 0, stream>>>(x, Wc, We, Wa, batch, cidx, eidx, WcT, WeT, WaT,
                                    c_off, c_cnt, c_pair, e_off, e_cnt, e_pair,
                                    bc, be, wcp_c, wep_c, xc_c, xe_c, c_flag, e_flag);
  k_attn<<<NG * DSLICES, 512, 0, stream>>>(xc_c, xe_c, wcp_c, wep_c,
                                           c_off, c_cnt, e_off, e_cnt, mcb);
  k_out<<<32, 512, 0, stream>>>(mcb, WaT, ba, out);
}

// Round 16
// 57.062 us; speedup vs baseline: 1.4801x; 1.4801x over previous
//
#include <hip/hip_runtime.h>
#include <hip/hip_bf16.h>

#define NHID 512
#define PROJ 64
#define NC 4096
#define NEV 8192
#define NG 64
#define NCMAX 128
#define NE_CAP 256
#define DSLICES 4
#define DW 128

typedef __attribute__((ext_vector_type(8))) short s16x8;
typedef __attribute__((ext_vector_type(8))) unsigned short u16x8;
typedef __attribute__((ext_vector_type(4))) float f32x4;

// ---- k_attn LDS layout (bytes) ----
#define P_S_STRIDE 264            // bf16 elems per row (256 + 8 pad), 528B
#define P_S_BYTES  (NCMAX * P_S_STRIDE * 2)        // 67584
#define REGB_OFF   P_S_BYTES
#define WE_S_STRIDE 72            // bf16 elems (64 + 8 pad), 144B
#define WC_S_OFF   (REGB_OFF + NE_CAP * WE_S_STRIDE * 2)
#define CN_S_STRIDE 132           // f32 elems per row
#define SMEM_BYTES (REGB_OFF + P_S_BYTES)

static __device__ __forceinline__ unsigned short f2b(float f) {
  union { __hip_bfloat16 h; unsigned short u; } v;
  v.h = __float2bfloat16(f);
  return v.u;
}
static __device__ __forceinline__ float b2f(unsigned short u) {
  union { unsigned short u; __hip_bfloat16 h; } v;
  v.u = u;
  return __bfloat162float(v.h);
}

// ---------------- compact_pairs: stable compaction -> (orig_pos, node_id) ----------------
template <int NPT>
__device__ __forceinline__ void compact_pairs(
    const int* __restrict__ batch, const int* __restrict__ idx, int g,
    int* __restrict__ off_out, int* __restrict__ cnt_out, int2* __restrict__ pairs) {
  __shared__ int wtot[4], wless[4];
  int t = threadIdx.x, lane = t & 63, w = t >> 6;
  int vals[NPT], nid[NPT];
  int base_i = t * NPT;
  int eq = 0, less = 0;
#pragma unroll
  for (int j = 0; j < NPT; j++) {
    int node = idx[base_i + j];
    int v = batch[node];
    vals[j] = v;
    nid[j] = node;
    eq += (v == g) ? 1 : 0;
    less += (v < g) ? 1 : 0;
  }
  int s = eq;
#pragma unroll
  for (int off = 1; off < 64; off <<= 1) {
    int o = __shfl_up(s, off);
    if (lane >= off) s += o;
  }
  int ls = less;
#pragma unroll
  for (int off = 32; off; off >>= 1) ls += __shfl_xor(ls, off);
  if (lane == 63) wtot[w] = s;
  if (lane == 0) wless[w] = ls;
  __syncthreads();
  int wbase = 0;
#pragma unroll
  for (int k = 0; k < 4; k++)
    if (k < w) wbase += wtot[k];
  int base = wless[0] + wless[1] + wless[2] + wless[3];
  int pos = base + wbase + (s - eq);
#pragma unroll
  for (int j = 0; j < NPT; j++) {
    if (vals[j] == g) pairs[pos++] = make_int2(base_i + j, nid[j]);
  }
  if (t == 255) {
    cnt_out[g] = wbase + s;
    off_out[g] = base;
  }
}

// ---------------- k_front: Wc/We transposes (0..15) + claim comp (16..79) + evid comp (80..143) ----------------
__global__ __launch_bounds__(256) void k_front(
    const float* __restrict__ Wc, const float* __restrict__ We,
    unsigned short* __restrict__ WcT, unsigned short* __restrict__ WeT,
    const int* __restrict__ batch, const int* __restrict__ cidx,
    const int* __restrict__ eidx, int* __restrict__ c_off, int* __restrict__ c_cnt,
    int2* __restrict__ c_pair, int* __restrict__ e_off, int* __restrict__ e_cnt,
    int2* __restrict__ e_pair) {
  int b = blockIdx.x;
  if (b < 16) {
    __shared__ float ts[64][65];
    const float* src = (b < 8) ? Wc : We;
    unsigned short* dst = (b < 8) ? WcT : WeT;
    int k0 = (b & 7) * 64;
    int t = threadIdx.x;
    int c = t & 63, r0 = t >> 6;
#pragma unroll
    for (int p = 0; p < 16; p++) {
      int r = r0 * 16 + p;
      ts[r][c] = src[(size_t)(k0 + r) * 64 + c];
    }
    __syncthreads();
    int n = t >> 2, q = t & 3;
    unsigned short tmp[16];
#pragma unroll
    for (int j = 0; j < 16; j++) tmp[j] = f2b(ts[q * 16 + j][n]);
    u16x8* dp = (u16x8*)(dst + (size_t)n * NHID + k0 + q * 16);
    dp[0] = *(u16x8*)tmp;
    dp[1] = *(u16x8*)(tmp + 8);
  } else if (b < 80) {
    compact_pairs<NC / 256>(batch, cidx, b - 16, c_off, c_cnt, c_pair);
  } else {
    compact_pairs<NEV / 256>(batch, eidx, b - 80, e_off, e_cnt, e_pair);
  }
}

// ---------------- k_proj: compacted-order GEMM (768 blocks) + x bf16 row export + Wa transpose ----------------
__global__ __launch_bounds__(256) void k_proj(
    const float* __restrict__ x, const int2* __restrict__ c_pair,
    const int2* __restrict__ e_pair, const unsigned short* __restrict__ WcT,
    const unsigned short* __restrict__ WeT, const float* __restrict__ bc,
    const float* __restrict__ be, const float* __restrict__ Wa,
    unsigned short* __restrict__ WaT, unsigned short* __restrict__ wcp_c,
    unsigned short* __restrict__ wep_c, unsigned short* __restrict__ xc_c,
    unsigned short* __restrict__ xe_c) {
  __shared__ __align__(16) char sm[64 * 65 * 4];
  int b = blockIdx.x;
  int t = threadIdx.x;
  if (b >= 768) {
    int tb = b - 768;
    float(*ts)[65] = (float(*)[65])sm;
    int k0 = (tb >> 3) * 64, n0 = (tb & 7) * 64;
    int c = t & 63, r0 = t >> 6;
#pragma unroll
    for (int p = 0; p < 16; p++) {
      int r = r0 * 16 + p;
      ts[r][c] = Wa[(size_t)(k0 + r) * NHID + n0 + c];
    }
    __syncthreads();
    int n = t >> 2, q = t & 3;
    unsigned short tmp[16];
#pragma unroll
    for (int j = 0; j < 16; j++) tmp[j] = f2b(ts[q * 16 + j][n]);
    u16x8* dp = (u16x8*)(WaT + (size_t)(n0 + n) * (4 * NHID) + k0 + q * 16);
    dp[0] = *(u16x8*)tmp;
    dp[1] = *(u16x8*)(tmp + 8);
    return;
  }
  float(*red)[16][64] = (float(*)[16][64])sm;   // [4][16][64] = 16KB
  const int2* pair; const unsigned short* WT; const float* bias;
  unsigned short* out; unsigned short* xout; int base;
  if (b < NC / 16) { pair = c_pair; WT = WcT; bias = bc; out = wcp_c; xout = xc_c; base = b * 16; }
  else             { pair = e_pair; WT = WeT; bias = be; out = wep_c; xout = xe_c; base = (b - NC / 16) * 16; }
  int lane = t & 63, kh = t >> 6;     // kh = 4-way K-split
  int ln = lane & 15, kb = lane >> 4;
  const float* xr = x + (size_t)pair[base + ln].y * NHID + kh * 128;
  unsigned short* xw = xout + (size_t)(base + ln) * NHID + kh * 128;
  const unsigned short* wb = WT + kh * 128;
  f32x4 acc[4];
#pragma unroll
  for (int nt = 0; nt < 4; nt++) acc[nt] = (f32x4){0.f, 0.f, 0.f, 0.f};
#pragma unroll
  for (int kt = 0; kt < 4; kt++) {
    int k0 = kt * 32 + kb * 8;
    float4 p0 = *(const float4*)(xr + k0);
    float4 p1 = *(const float4*)(xr + k0 + 4);
    s16x8 a;
    a[0] = (short)f2b(p0.x); a[1] = (short)f2b(p0.y);
    a[2] = (short)f2b(p0.z); a[3] = (short)f2b(p0.w);
    a[4] = (short)f2b(p1.x); a[5] = (short)f2b(p1.y);
    a[6] = (short)f2b(p1.z); a[7] = (short)f2b(p1.w);
    *(u16x8*)(xw + k0) = (u16x8)a;   // export bf16 row (compacted order)
#pragma unroll
    for (int nt = 0; nt < 4; nt++) {
      s16x8 bf = *(const s16x8*)(wb + (size_t)(nt * 16 + ln) * NHID + k0);
      acc[nt] = __builtin_amdgcn_mfma_f32_16x16x32_bf16(a, bf, acc[nt], 0, 0, 0);
    }
  }
#pragma unroll
  for (int nt = 0; nt < 4; nt++)
#pragma unroll
    for (int r = 0; r < 4; r++)
      red[kh][kb * 4 + r][nt * 16 + ln] = acc[nt][r];
  __syncthreads();
  for (int i = t; i < 512; i += 256) {
    int row = i >> 5, cp = i & 31;
    int c0 = cp * 2;
    float v0 = red[0][row][c0] + red[1][row][c0] + red[2][row][c0] + red[3][row][c0] + bias[c0];
    float v1 = red[0][row][c0 + 1] + red[1][row][c0 + 1] + red[2][row][c0 + 1] + red[3][row][c0 + 1] + bias[c0 + 1];
    unsigned int pk = (unsigned)f2b(v0) | ((unsigned)f2b(v1) << 16);
    *(unsigned int*)(out + (size_t)(base + row) * PROJ + c0) = pk;
  }
}

// ---------------- k_attn: MFMA attention, fully-contiguous staging from compacted buffers ----------------
__global__ __launch_bounds__(512, 2) void k_attn(
    const unsigned short* __restrict__ xc_c, const unsigned short* __restrict__ xe_c,
    const unsigned short* __restrict__ wcp_c, const unsigned short* __restrict__ wep_c,
    const int* __restrict__ c_off, const int* __restrict__ c_cnt,
    const int* __restrict__ e_off, const int* __restrict__ e_cnt,
    unsigned short* __restrict__ mcb) {
  __shared__ __align__(16) char smem[SMEM_BYTES];
  unsigned short* P_s  = (unsigned short*)(smem);
  unsigned short* we_s = (unsigned short*)(smem + REGB_OFF);
  unsigned short* wc_s = (unsigned short*)(smem + WC_S_OFF);
  unsigned short* evT  = (unsigned short*)(smem + REGB_OFF);
  unsigned int*   evT32 = (unsigned int*)(smem + REGB_OFF);
  float*          cn_s = (float*)(smem + REGB_OFF);
  float*          pp   = (float*)(smem);          // reuses dead P_s region post-PV

  int g = blockIdx.x >> 2;
  int ds = blockIdx.x & 3;
  int dsbase = ds * DW;
  int t = threadIdx.x, lane = t & 63, w = t >> 6;
  int ln = lane & 15, kb = lane >> 4;

  int ne = min(e_cnt[g], NE_CAP);
  int eoff = e_off[g];
  int ccnt_full = c_cnt[g];
  int nloc = min(ccnt_full, NCMAX);
  int coff = c_off[g];
  if (nloc <= 0) {
    int q = t >> 7, d = t & 127;
    mcb[(size_t)g * 4 * NHID + q * NHID + dsbase + d] = 0;
    return;
  }
  int KT = (ne + 31) >> 5;
  int NT = KT * 2;

  // ---- phase 0: stage we_s + wc_s (CONTIGUOUS copies from compacted buffers) ----
  {
    int q = t & 7, er = t >> 3;
    for (int base_ = 0; base_ < NE_CAP; base_ += 64) {
      int e = base_ + er;
      u16x8 v = (u16x8){0, 0, 0, 0, 0, 0, 0, 0};
      if (e < ne) v = *(const u16x8*)(wep_c + (size_t)(eoff + e) * PROJ + q * 8);
      *(u16x8*)(we_s + e * WE_S_STRIDE + q * 8) = v;
    }
    for (int base_ = 0; base_ < NCMAX; base_ += 64) {
      int c = base_ + er;
      u16x8 v = (u16x8){0, 0, 0, 0, 0, 0, 0, 0};
      if (c < nloc) v = *(const u16x8*)(wcp_c + (size_t)(coff + c) * PROJ + q * 8);
      *(u16x8*)(wc_s + c * WE_S_STRIDE + q * 8) = v;
    }
  }
  __syncthreads();

  // ---- score phase: S = wc @ we^T via MFMA ----
  {
    f32x4 sa[16];
#pragma unroll
    for (int i = 0; i < 16; i++) sa[i] = (f32x4){0.f, 0.f, 0.f, 0.f};
    const unsigned short* arow = wc_s + ((w << 4) + ln) * WE_S_STRIDE;
#pragma unroll
    for (int ks = 0; ks < 2; ks++) {
      s16x8 af = *(const s16x8*)(arow + ks * 32 + kb * 8);
#pragma unroll
      for (int nt = 0; nt < 16; nt++) {
        if (nt < NT) {
          s16x8 bf = *(const s16x8*)(we_s + (nt * 16 + ln) * WE_S_STRIDE + ks * 32 + kb * 8);
          sa[nt] = __builtin_amdgcn_mfma_f32_16x16x32_bf16(af, bf, sa[nt], 0, 0, 0);
        }
      }
    }
#pragma unroll
    for (int r = 0; r < 4; r++) {
      int claim = (w << 4) + (kb << 2) + r;
      float mx = -1e30f;
#pragma unroll
      for (int nt = 0; nt < 16; nt++) {
        if (nt < NT) {
          float v = sa[nt][r];
          v = (nt * 16 + ln < ne) ? v : -1e30f;
          sa[nt][r] = v;
          mx = fmaxf(mx, v);
        }
      }
      mx = fmaxf(mx, __shfl_xor(mx, 1));
      mx = fmaxf(mx, __shfl_xor(mx, 2));
      mx = fmaxf(mx, __shfl_xor(mx, 4));
      mx = fmaxf(mx, __shfl_xor(mx, 8));
      float sum = 0.f;
#pragma unroll
      for (int nt = 0; nt < 16; nt++) {
        if (nt < NT) {
          float p = __expf(sa[nt][r] - mx);
          sa[nt][r] = p;
          sum += p;
        }
      }
      sum += __shfl_xor(sum, 1);
      sum += __shfl_xor(sum, 2);
      sum += __shfl_xor(sum, 4);
      sum += __shfl_xor(sum, 8);
      float inv = 1.f / sum;
#pragma unroll
      for (int nt = 0; nt < 16; nt++) {
        if (nt < NT)
          P_s[claim * P_S_STRIDE + nt * 16 + ln] = f2b(sa[nt][r] * inv);
      }
    }
  }
  __syncthreads();   // we_s dead; P_s ready

  // ---- evT staging: contiguous bf16 slab, (ep8 x j8) lane map ----
  // global: 128B contiguous per (row, j8-group); LDS: 8-way write conflict max.
#pragma unroll
  for (int it = 0; it < 4; it++) {
    int idx2 = it * 512 + t;              // [ep_hi:4][j8:4][ep_lo:3]
    int ep = ((idx2 >> 7) << 3) | (idx2 & 7);
    int j8 = (idx2 >> 3) & 15;
    int d0 = j8 * 8;
    int e0 = ep * 2;
    u16x8 va = (u16x8){0, 0, 0, 0, 0, 0, 0, 0};
    u16x8 vb = (u16x8){0, 0, 0, 0, 0, 0, 0, 0};
    if (e0 < ne)     va = *(const u16x8*)(xe_c + (size_t)(eoff + e0) * NHID + dsbase + d0);
    if (e0 + 1 < ne) vb = *(const u16x8*)(xe_c + (size_t)(eoff + e0 + 1) * NHID + dsbase + d0);
#pragma unroll
    for (int j = 0; j < 8; j++)
      evT32[(d0 + j) * (P_S_STRIDE / 2) + ep] =
          (unsigned)(unsigned short)va[j] | ((unsigned)(unsigned short)vb[j] << 16);
  }
  __syncthreads();

  // ---- T14: issue claim-row loads (bf16, contiguous) for pooled phase ----
  int dq4 = (t & 31) * 4;
  int mg = t >> 5;     // 0..15
  ushort4 cl_u[8];
#pragma unroll
  for (int mi = 0; mi < 8; mi++) {
    int m = mg + mi * 16;
    cl_u[mi] = make_ushort4(0, 0, 0, 0);
    if (m < nloc)
      cl_u[mi] = *(const ushort4*)(xc_c + (size_t)(coff + m) * NHID + dsbase + dq4);
  }

  // ---- PV phase ----
  int mw = w >> 1, nw = w & 1;
  int m0 = mw * 32, n0 = nw * 64;
  f32x4 pc[8];
#pragma unroll
  for (int i = 0; i < 8; i++) pc[i] = (f32x4){0.f, 0.f, 0.f, 0.f};
  {
    const unsigned short* prow0 = P_s + (m0 + ln) * P_S_STRIDE + kb * 8;
    const unsigned short* prow1 = prow0 + 16 * P_S_STRIDE;
#pragma unroll
    for (int kt = 0; kt < 8; kt++) {
      if (kt < KT) {
        int k0 = kt * 32;
        s16x8 a0 = *(const s16x8*)(prow0 + k0);
        s16x8 a1 = *(const s16x8*)(prow1 + k0);
#pragma unroll
        for (int nt = 0; nt < 4; nt++) {
          s16x8 bf = *(const s16x8*)(evT + (n0 + nt * 16 + ln) * P_S_STRIDE + k0 + kb * 8);
          pc[nt]     = __builtin_amdgcn_mfma_f32_16x16x32_bf16(a0, bf, pc[nt], 0, 0, 0);
          pc[4 + nt] = __builtin_amdgcn_mfma_f32_16x16x32_bf16(a1, bf, pc[4 + nt], 0, 0, 0);
        }
      }
    }
  }
  __syncthreads();   // P_s dead from here; pp may reuse its region

  // ---- dump cn to LDS ----
#pragma unroll
  for (int mi = 0; mi < 2; mi++) {
#pragma unroll
    for (int nt = 0; nt < 4; nt++) {
      f32x4 v = pc[mi * 4 + nt];
#pragma unroll
      for (int r = 0; r < 4; r++)
        cn_s[(m0 + mi * 16 + (kb << 2) + r) * CN_S_STRIDE + n0 + nt * 16 + ln] = v[r];
    }
  }
  __syncthreads();

  // ---- pooled sums: staged bf16 claim regs + cn_s, partials into pp ----
  {
    float4 scl = make_float4(0.f, 0.f, 0.f, 0.f);
    float4 scn = make_float4(0.f, 0.f, 0.f, 0.f);
    float4 spr = make_float4(0.f, 0.f, 0.f, 0.f);
#pragma unroll
    for (int mi = 0; mi < 8; mi++) {
      int m = mg + mi * 16;
      if (m < nloc) {
        float clx = b2f(cl_u[mi].x), cly = b2f(cl_u[mi].y);
        float clz = b2f(cl_u[mi].z), clw = b2f(cl_u[mi].w);
        float4 cn = *(const float4*)(cn_s + m * CN_S_STRIDE + dq4);
        scl.x += clx; scl.y += cly; scl.z += clz; scl.w += clw;
        scn.x += cn.x; scn.y += cn.y; scn.z += cn.z; scn.w += cn.w;
        spr.x += clx * cn.x; spr.y += cly * cn.y;
        spr.z += clz * cn.z; spr.w += clw * cn.w;
      }
    }
    *(float4*)(pp + mg * 128 + dq4) = scl;
    *(float4*)(pp + 2048 + mg * 128 + dq4) = scn;
    *(float4*)(pp + 4096 + mg * 128 + dq4) = spr;
  }
  __syncthreads();

  // ---- fused mean-concat epilogue ----
  {
    int q = t >> 7, d = t & 127;
    float inv = 1.f / (float)max(ccnt_full, 1);
    float v = 0.f;
    if (q == 0) {
#pragma unroll
      for (int mg2 = 0; mg2 < 16; mg2++) v += pp[mg2 * 128 + d];
    } else if (q == 1) {
#pragma unroll
      for (int mg2 = 0; mg2 < 16; mg2++) v += pp[2048 + mg2 * 128 + d];
    } else if (q == 2) {
#pragma unroll
      for (int mg2 = 0; mg2 < 16; mg2++) v += pp[mg2 * 128 + d] - pp[2048 + mg2 * 128 + d];
    } else {
#pragma unroll
      for (int mg2 = 0; mg2 < 16; mg2++) v += pp[4096 + mg2 * 128 + d];
    }
    mcb[(size_t)g * 4 * NHID + q * NHID + dsbase + d] = f2b(v * inv);
  }
}

// ---------------- k_out: 32 blocks, 16-col n-tiles, 2-way K-split ----------------
__global__ __launch_bounds__(512) void k_out(
    const unsigned short* __restrict__ mc, const unsigned short* __restrict__ WaT,
    const float* __restrict__ ba, float* __restrict__ out) {
  __shared__ float red[2][64][16];   // 8KB
  int n0 = blockIdx.x * 16;
  int t = threadIdx.x, lane = t & 63, wv = t >> 6;
  int mh = wv & 3, kh = wv >> 2;
  int ln = lane & 15, kb = lane >> 4;
  f32x4 acc = (f32x4){0.f, 0.f, 0.f, 0.f};
  const unsigned short* arow = mc + (size_t)(mh * 16 + ln) * (4 * NHID) + kh * 1024;
  const unsigned short* wcol = WaT + (size_t)(n0 + ln) * (4 * NHID) + kh * 1024;
#pragma unroll 4
  for (int kt = 0; kt < 32; kt++) {
    int k0 = kt * 32 + kb * 8;
    s16x8 af = *(const s16x8*)(arow + k0);
    s16x8 bf = *(const s16x8*)(wcol + k0);
    acc = __builtin_amdgcn_mfma_f32_16x16x32_bf16(af, bf, acc, 0, 0, 0);
  }
#pragma unroll
  for (int r = 0; r < 4; r++)
    red[kh][mh * 16 + kb * 4 + r][ln] = acc[r];
  __syncthreads();
  for (int i = t; i < 1024; i += 512) {
    int row = i >> 4, col = i & 15;
    out[(size_t)row * NHID + n0 + col] = red[0][row][col] + red[1][row][col] + ba[n0 + col];
  }
}

extern "C" void kernel_launch(void* const* d_in, const int* in_sizes, int n_in,
                              void* d_out, int out_size, void* d_ws, size_t ws_size,
                              hipStream_t stream) {
  const float* x = (const float*)d_in[0];
  const int* batch = (const int*)d_in[1];
  const int* cidx = (const int*)d_in[2];
  const int* eidx = (const int*)d_in[3];
  const float* Wc = (const float*)d_in[4];
  const float* bc = (const float*)d_in[5];
  const float* We = (const float*)d_in[6];
  const float* be = (const float*)d_in[7];
  const float* Wa = (const float*)d_in[8];
  const float* ba = (const float*)d_in[9];
  float* out = (float*)d_out;

  char* w = (char*)d_ws;
  int* c_off = (int*)w;    w += NG * 4;
  int* c_cnt = (int*)w;    w += NG * 4;
  int* e_off = (int*)w;    w += NG * 4;
  int* e_cnt = (int*)w;    w += NG * 4;
  int2* c_pair = (int2*)w; w += (size_t)NC * 8;
  int2* e_pair = (int2*)w; w += (size_t)NEV * 8;
  unsigned short* wcp_c = (unsigned short*)w; w += (size_t)NC * PROJ * 2;
  unsigned short* wep_c = (unsigned short*)w; w += (size_t)NEV * PROJ * 2;
  unsigned short* WcT = (unsigned short*)w;   w += (size_t)PROJ * NHID * 2;
  unsigned short* WeT = (unsigned short*)w;   w += (size_t)PROJ * NHID * 2;
  unsigned short* WaT = (unsigned short*)w;   w += (size_t)NHID * 4 * NHID * 2;
  unsigned short* mcb = (unsigned short*)w;   w += (size_t)NG * 4 * NHID * 2;
  unsigned short* xc_c = (unsigned short*)w;  w += (size_t)NC * NHID * 2;
  unsigned short* xe_c = (unsigned short*)w;  w += (size_t)NEV * NHID * 2;

  k_front<<<144, 256, 0, stream>>>(Wc, We, WcT, WeT, batch, cidx, eidx,
                                   c_off, c_cnt, c_pair, e_off, e_cnt, e_pair);
  k_proj<<<768 + 256, 256, 0, stream>>>(x, c_pair, e_pair, WcT, WeT, bc, be, Wa, WaT,
                                        wcp_c, wep_c, xc_c, xe_c);
  k_attn<<<NG * DSLICES, 512, 0, stream>>>(xc_c, xe_c, wcp_c, wep_c,
                                           c_off, c_cnt, e_off, e_cnt, mcb);
  k_out<<<32, 512, 0, stream>>>(mcb, WaT, ba, out);
}